// Round 2
// baseline (226.864 us; speedup 1.0000x reference)
//
#include <hip/hip_runtime.h>

typedef unsigned short ushort_t;
typedef __attribute__((ext_vector_type(4))) float f32x4;
typedef __attribute__((ext_vector_type(8))) short s16x8;
typedef __attribute__((ext_vector_type(4))) unsigned int u32x4;

#define LOG2E 1.44269504088896340736f

__device__ inline unsigned short bf16_rne(float f) {
    unsigned u = __builtin_bit_cast(unsigned, f);
    unsigned r = u + 0x7FFFu + ((u >> 16) & 1u);
    return (unsigned short)(r >> 16);
}

__device__ inline f32x4 mfma16(s16x8 a, s16x8 b, f32x4 c) {
    return __builtin_amdgcn_mfma_f32_16x16x32_bf16(a, b, c, 0, 0, 0);
}

// ---------------- conversion kernels ----------------

__global__ __launch_bounds__(256) void cvt_x_kernel(const float* __restrict__ x,
                                                    unsigned short* __restrict__ xb, int n8) {
    int i = blockIdx.x * 256 + threadIdx.x;
    if (i >= n8) return;
    const float4* xp = (const float4*)x + (size_t)i * 2;
    float4 a = xp[0], b = xp[1];
    unsigned short r[8] = {bf16_rne(a.x), bf16_rne(a.y), bf16_rne(a.z), bf16_rne(a.w),
                           bf16_rne(b.x), bf16_rne(b.y), bf16_rne(b.z), bf16_rne(b.w)};
    *(u32x4*)(xb + (size_t)i * 8) = *(u32x4*)r;
}

// dst[c][r] = bf16(src[r][c]);  dst row length = Rr
__global__ __launch_bounds__(256) void cvt_t_kernel(const float* __restrict__ src,
                                                    unsigned short* __restrict__ dst, int Rr, int Cc) {
    int i = blockIdx.x * 256 + threadIdx.x;
    if (i >= Rr * Cc) return;
    int r = i / Cc, c = i % Cc;
    dst[(size_t)c * Rr + r] = bf16_rne(src[i]);
}

// ---------------- GEMM: C[M,N] = A[M,K] * BT[N,K]^T  (bf16 in, bf16/f32 out) --------------

template <int OUTF>
__global__ __launch_bounds__(256) void gemm128(const unsigned short* __restrict__ A,
                                               const unsigned short* __restrict__ BT,
                                               void* __restrict__ Cv,
                                               const float* __restrict__ bias,
                                               int M, int N, int K) {
    __shared__ unsigned short Alds[128 * 64];
    __shared__ unsigned short Blds[128 * 64];
    const int t = threadIdx.x, lane = t & 63, wv = t >> 6;
    const int wm = wv >> 1, wn = wv & 1;
    const int tm = blockIdx.y, tn = blockIdx.x;

    f32x4 acc[4][4];
#pragma unroll
    for (int mf = 0; mf < 4; mf++)
#pragma unroll
        for (int nf = 0; nf < 4; nf++) acc[mf][nf] = f32x4{0.f, 0.f, 0.f, 0.f};

    const int nkt = K >> 6;
    for (int kt = 0; kt < nkt; kt++) {
        __syncthreads();
#pragma unroll
        for (int i = 0; i < 4; i++) {
            int ul = i * 256 + t;
            int row = ul >> 3, u = ul & 7;
            u32x4 av = *(const u32x4*)(A + (size_t)(tm * 128 + row) * K + kt * 64 + u * 8);
            *(u32x4*)((char*)Alds + row * 128 + ((u ^ (row & 7)) << 4)) = av;
            u32x4 bv = *(const u32x4*)(BT + (size_t)(tn * 128 + row) * K + kt * 64 + u * 8);
            *(u32x4*)((char*)Blds + row * 128 + ((u ^ (row & 7)) << 4)) = bv;
        }
        __syncthreads();
#pragma unroll
        for (int ks = 0; ks < 2; ks++) {
            s16x8 af[4], bf[4];
#pragma unroll
            for (int mf = 0; mf < 4; mf++) {
                int row = wm * 64 + mf * 16 + (lane & 15);
                af[mf] = *(const s16x8*)((char*)Alds + row * 128 +
                                         ((((ks << 2) | (lane >> 4)) ^ (row & 7)) << 4));
            }
#pragma unroll
            for (int nf = 0; nf < 4; nf++) {
                int row = wn * 64 + nf * 16 + (lane & 15);
                bf[nf] = *(const s16x8*)((char*)Blds + row * 128 +
                                         ((((ks << 2) | (lane >> 4)) ^ (row & 7)) << 4));
            }
#pragma unroll
            for (int mf = 0; mf < 4; mf++)
#pragma unroll
                for (int nf = 0; nf < 4; nf++) acc[mf][nf] = mfma16(af[mf], bf[nf], acc[mf][nf]);
        }
    }

#pragma unroll
    for (int mf = 0; mf < 4; mf++) {
#pragma unroll
        for (int r = 0; r < 4; r++) {
            int row = tm * 128 + wm * 64 + mf * 16 + (lane >> 4) * 4 + r;
#pragma unroll
            for (int nf = 0; nf < 4; nf++) {
                int col = tn * 128 + wn * 64 + nf * 16 + (lane & 15);
                float v = acc[mf][nf][r];
                if constexpr (OUTF) {
                    ((float*)Cv)[(size_t)row * N + col] = v + bias[col];
                } else {
                    ((unsigned short*)Cv)[(size_t)row * N + col] = bf16_rne(v);
                }
            }
        }
    }
}

// ---------------- window attention, r in {8,16,32} ----------------
// qkv layout: [b*4096 + n][1536] bf16; q at col h*64, k at 512+h*64, v at 1024+h*64.
// One block = 64 Q-rows of one window (4 waves x 16 rows); KV chunked by 64 tokens via LDS.

template <int R>
__global__ __launch_bounds__(256) void attn_win(const unsigned short* __restrict__ qkv,
                                                unsigned short* __restrict__ ob) {
    constexpr int L = R * R;
    constexpr int NCH = L / 64;
    constexpr int WPD = 64 / R;       // windows per dim
    constexpr int NWIN = WPD * WPD;
    constexpr int HEAD0 = (R == 8) ? 2 : ((R == 16) ? 4 : 6);

    __shared__ unsigned short Klds[64 * 64];   // [tok][dim], XOR-swizzled 16B units
    __shared__ unsigned short VTlds[64 * 64];  // [dim][tok], XOR-swizzled
    __shared__ unsigned short Plds[4][16 * 64];// per-wave [qrow][tok], swizzled

    const int t = threadIdx.x;
    const int lane = t & 63;
    const int wv = t >> 6;

    const int bpw = L / 64;
    int g = blockIdx.x;
    int wid = g / bpw;
    int qc = g % bpw;
    int w = wid % NWIN;
    int hb = wid / NWIN;
    int b = hb & 3;
    int head = HEAD0 + (hb >> 2);
    int wy = w / WPD, wx = w % WPD;

    const unsigned short* qbase = qkv + (size_t)b * 4096 * 1536;

    // Q fragments (A operand), rows = qc*64 + wv*16 + (lane&15)
    int qrow_w = qc * 64 + wv * 16 + (lane & 15);
    int qn = (wy * R + qrow_w / R) * 64 + wx * R + qrow_w % R;
    s16x8 qf[2];
    {
        const unsigned short* qp = qbase + (size_t)qn * 1536 + head * 64 + (lane >> 4) * 8;
        qf[0] = *(const s16x8*)(qp);
        qf[1] = *(const s16x8*)(qp + 32);
    }

    f32x4 o[4];
    float mrun[4], lrun[4];
#pragma unroll
    for (int i = 0; i < 4; i++) {
        o[i] = f32x4{0.f, 0.f, 0.f, 0.f};
        mrun[i] = -1e30f;
        lrun[i] = 0.f;
    }

    for (int c = 0; c < NCH; c++) {
        __syncthreads();
        // stage K chunk (64 tok x 64 dim)
#pragma unroll
        for (int i = 0; i < 2; i++) {
            int ul = i * 256 + t;
            int tok = ul >> 3, u = ul & 7;
            int tw = c * 64 + tok;
            int n = (wy * R + tw / R) * 64 + wx * R + tw % R;
            u32x4 d = *(const u32x4*)(qbase + (size_t)n * 1536 + 512 + head * 64 + u * 8);
            *(u32x4*)((char*)Klds + tok * 128 + ((u ^ (tok & 7)) << 4)) = d;
        }
        // stage V transposed: VT[dim][tok]
        {
            int tok = t & 63, dgrp = t >> 6;
            int tw = c * 64 + tok;
            int n = (wy * R + tw / R) * 64 + wx * R + tw % R;
            const unsigned short* vp = qbase + (size_t)n * 1536 + 1024 + head * 64;
#pragma unroll
            for (int i = 0; i < 2; i++) {
                int dim0 = dgrp * 8 + i * 32;
                u32x4 d = *(const u32x4*)(vp + dim0);
                const unsigned short* dsv = (const unsigned short*)&d;
#pragma unroll
                for (int j = 0; j < 8; j++) {
                    int dim = dim0 + j;
                    *(unsigned short*)((char*)VTlds + dim * 128 +
                                       ((((tok >> 3) ^ (dim & 7))) << 4) + (tok & 7) * 2) = dsv[j];
                }
            }
        }
        __syncthreads();

        // S = Q K^T
        f32x4 s[4];
#pragma unroll
        for (int cf = 0; cf < 4; cf++) s[cf] = f32x4{0.f, 0.f, 0.f, 0.f};
#pragma unroll
        for (int ks = 0; ks < 2; ks++) {
#pragma unroll
            for (int cf = 0; cf < 4; cf++) {
                int tok = cf * 16 + (lane & 15);
                s16x8 kb = *(const s16x8*)((char*)Klds + tok * 128 +
                                           ((((ks << 2) | (lane >> 4)) ^ (tok & 7)) << 4));
                s[cf] = mfma16(qf[ks], kb, s[cf]);
            }
        }
#pragma unroll
        for (int cf = 0; cf < 4; cf++) s[cf] *= 0.125f;

        // online softmax; row r of lane = (lane>>4)*4 + r, cols = cf*16 + (lane&15)
        float pm[4];
#pragma unroll
        for (int r = 0; r < 4; r++)
            pm[r] = fmaxf(fmaxf(s[0][r], s[1][r]), fmaxf(s[2][r], s[3][r]));
#pragma unroll
        for (int m = 1; m < 16; m <<= 1)
#pragma unroll
            for (int r = 0; r < 4; r++) pm[r] = fmaxf(pm[r], __shfl_xor(pm[r], m, 64));

        float mnew[4], corr[4];
#pragma unroll
        for (int r = 0; r < 4; r++) {
            mnew[r] = fmaxf(mrun[r], pm[r]);
            corr[r] = exp2f((mrun[r] - mnew[r]) * LOG2E);
            mrun[r] = mnew[r];
        }
        float rs[4] = {0.f, 0.f, 0.f, 0.f};
        unsigned short pu[4][4];
#pragma unroll
        for (int cf = 0; cf < 4; cf++)
#pragma unroll
            for (int r = 0; r < 4; r++) {
                float p = exp2f((s[cf][r] - mnew[r]) * LOG2E);
                rs[r] += p;
                pu[cf][r] = bf16_rne(p);
            }
#pragma unroll
        for (int m = 1; m < 16; m <<= 1)
#pragma unroll
            for (int r = 0; r < 4; r++) rs[r] += __shfl_xor(rs[r], m, 64);
#pragma unroll
        for (int r = 0; r < 4; r++) lrun[r] = lrun[r] * corr[r] + rs[r];
#pragma unroll
        for (int nf = 0; nf < 4; nf++)
#pragma unroll
            for (int r = 0; r < 4; r++) o[nf][r] *= corr[r];

        // P -> per-wave LDS (transpose to A layout)
        unsigned short* pw = Plds[wv];
#pragma unroll
        for (int cf = 0; cf < 4; cf++) {
            int col = cf * 16 + (lane & 15);
#pragma unroll
            for (int r = 0; r < 4; r++) {
                int row = (lane >> 4) * 4 + r;
                *(unsigned short*)((char*)pw + row * 128 + (((col >> 3) ^ (row & 7)) << 4) +
                                   (col & 7) * 2) = pu[cf][r];
            }
        }
        asm volatile("s_waitcnt lgkmcnt(0)" ::: "memory");

        // O += P V
#pragma unroll
        for (int ks = 0; ks < 2; ks++) {
            int prow = lane & 15;
            s16x8 pa = *(const s16x8*)((char*)pw + prow * 128 +
                                       ((((ks << 2) | (lane >> 4)) ^ (prow & 7)) << 4));
#pragma unroll
            for (int nf = 0; nf < 4; nf++) {
                int dim = nf * 16 + (lane & 15);
                s16x8 vb = *(const s16x8*)((char*)VTlds + dim * 128 +
                                           ((((ks << 2) | (lane >> 4)) ^ (dim & 7)) << 4));
                o[nf] = mfma16(pa, vb, o[nf]);
            }
        }
    }

    // epilogue
#pragma unroll
    for (int r = 0; r < 4; r++) {
        int qr = qc * 64 + wv * 16 + (lane >> 4) * 4 + r;
        int n = (wy * R + qr / R) * 64 + wx * R + qr % R;
        float inv = 1.0f / lrun[r];
        unsigned short* op = ob + ((size_t)b * 4096 + n) * 512 + head * 64 + (lane & 15);
#pragma unroll
        for (int nf = 0; nf < 4; nf++) op[nf * 16] = bf16_rne(o[nf][r] * inv);
    }
}

// ---------------- window attention r=4 (L=16): one wave per window ----------------

__global__ __launch_bounds__(256) void attn_win4(const unsigned short* __restrict__ qkv,
                                                 unsigned short* __restrict__ ob) {
    __shared__ unsigned short VTlds[4][64 * 32];  // per-wave [dim][tok(32, upper half zero)]
    __shared__ unsigned short Plds[4][16 * 32];   // per-wave [qrow][tok(32)]
    const int t = threadIdx.x, lane = t & 63, wv = t >> 6;
    int gwin = blockIdx.x * 4 + wv;  // ((hh*4+b)*256 + w)
    int w = gwin & 255;
    int hb = gwin >> 8;
    int b = hb & 3;
    int head = hb >> 2;  // heads 0,1
    int wy = w >> 4, wx = w & 15;
    const unsigned short* qbase = qkv + (size_t)b * 4096 * 1536;

    int qtok = lane & 15;
    int qn = (wy * 4 + (qtok >> 2)) * 64 + wx * 4 + (qtok & 3);
    const unsigned short* qp = qbase + (size_t)qn * 1536 + head * 64 + (lane >> 4) * 8;
    s16x8 qf0 = *(const s16x8*)(qp);
    s16x8 qf1 = *(const s16x8*)(qp + 32);

    int kn = qn;  // B-frag col token = lane&15 -> same mapping
    const unsigned short* kp = qbase + (size_t)kn * 1536 + 512 + head * 64 + (lane >> 4) * 8;
    s16x8 kb0 = *(const s16x8*)(kp);
    s16x8 kb1 = *(const s16x8*)(kp + 32);

    f32x4 s = f32x4{0.f, 0.f, 0.f, 0.f};
    s = mfma16(qf0, kb0, s);
    s = mfma16(qf1, kb1, s);
    s *= 0.125f;

    // stage V transposed (per wave), zero-pad tokens 16..31
    unsigned short* vt = VTlds[wv];
    {
        int tok = lane & 15, dgrp = lane >> 4;
        int vn = (wy * 4 + (tok >> 2)) * 64 + wx * 4 + (tok & 3);
        const unsigned short* vp = qbase + (size_t)vn * 1536 + 1024 + head * 64;
#pragma unroll
        for (int i = 0; i < 2; i++) {
            int dim0 = dgrp * 8 + i * 32;
            u32x4 d = *(const u32x4*)(vp + dim0);
            const unsigned short* dsv = (const unsigned short*)&d;
#pragma unroll
            for (int j = 0; j < 8; j++) {
                int dim = dim0 + j;
                vt[dim * 32 + tok] = dsv[j];
                vt[dim * 32 + 16 + tok] = 0;
            }
        }
    }

    // softmax (single chunk of 16 cols)
    float pm[4];
#pragma unroll
    for (int r = 0; r < 4; r++) pm[r] = s[r];
#pragma unroll
    for (int m = 1; m < 16; m <<= 1)
#pragma unroll
        for (int r = 0; r < 4; r++) pm[r] = fmaxf(pm[r], __shfl_xor(pm[r], m, 64));

    float l4[4];
    unsigned short pu[4];
#pragma unroll
    for (int r = 0; r < 4; r++) {
        float p = exp2f((s[r] - pm[r]) * LOG2E);
        pu[r] = bf16_rne(p);
        l4[r] = p;
    }
#pragma unroll
    for (int m = 1; m < 16; m <<= 1)
#pragma unroll
        for (int r = 0; r < 4; r++) l4[r] += __shfl_xor(l4[r], m, 64);

    unsigned short* pl = Plds[wv];
#pragma unroll
    for (int r = 0; r < 4; r++) {
        int row = (lane >> 4) * 4 + r;
        pl[row * 32 + (lane & 15)] = pu[r];
        pl[row * 32 + 16 + (lane & 15)] = 0;
    }
    asm volatile("s_waitcnt lgkmcnt(0)" ::: "memory");

    s16x8 pa = *(const s16x8*)(pl + (lane & 15) * 32 + (lane >> 4) * 8);
    f32x4 o[4];
#pragma unroll
    for (int nf = 0; nf < 4; nf++) {
        s16x8 vb = *(const s16x8*)(vt + (nf * 16 + (lane & 15)) * 32 + (lane >> 4) * 8);
        o[nf] = mfma16(pa, vb, f32x4{0.f, 0.f, 0.f, 0.f});
    }

#pragma unroll
    for (int r = 0; r < 4; r++) {
        int qr = (lane >> 4) * 4 + r;
        int n = (wy * 4 + (qr >> 2)) * 64 + wx * 4 + (qr & 3);
        float inv = 1.0f / l4[r];
        unsigned short* op = ob + ((size_t)b * 4096 + n) * 512 + head * 64 + (lane & 15);
#pragma unroll
        for (int nf = 0; nf < 4; nf++) op[nf * 16] = bf16_rne(o[nf][r] * inv);
    }
}

// ---------------- launcher ----------------

extern "C" void kernel_launch(void* const* d_in, const int* in_sizes, int n_in,
                              void* d_out, int out_size, void* d_ws, size_t ws_size,
                              hipStream_t stream) {
    (void)in_sizes; (void)n_in; (void)out_size; (void)ws_size;
    const float* x = (const float*)d_in[0];
    const float* Wq = (const float*)d_in[1];
    const float* Wkv = (const float*)d_in[2];
    const float* Wproj = (const float*)d_in[3];
    const float* bproj = (const float*)d_in[4];

    char* ws = (char*)d_ws;
    unsigned short* qkv = (unsigned short*)ws;                                   // 16384*1536 bf16 (48MB)
    unsigned short* xb = (unsigned short*)(ws + (size_t)16384 * 1536 * 2);       // 16384*512 (16MB), reused as ob
    unsigned short* WcatT = (unsigned short*)(ws + (size_t)16384 * 1536 * 2 + (size_t)16384 * 512 * 2);
    unsigned short* WprojT = WcatT + (size_t)1536 * 512;
    unsigned short* ob = xb;  // xb dead after gemm_qkv; alias to save workspace

    cvt_x_kernel<<<4096, 256, 0, stream>>>(x, xb, 16384 * 512 / 8);
    cvt_t_kernel<<<1024, 256, 0, stream>>>(Wq, WcatT, 512, 512);
    cvt_t_kernel<<<2048, 256, 0, stream>>>(Wkv, WcatT + (size_t)512 * 512, 512, 1024);
    cvt_t_kernel<<<1024, 256, 0, stream>>>(Wproj, WprojT, 512, 512);

    gemm128<0><<<dim3(12, 128), 256, 0, stream>>>(xb, WcatT, (void*)qkv, nullptr, 16384, 1536, 512);

    attn_win4<<<512, 256, 0, stream>>>(qkv, ob);
    attn_win<8><<<512, 256, 0, stream>>>(qkv, ob);
    attn_win<16><<<512, 256, 0, stream>>>(qkv, ob);
    attn_win<32><<<512, 256, 0, stream>>>(qkv, ob);

    gemm128<1><<<dim3(4, 128), 256, 0, stream>>>(ob, WprojT, d_out, bproj, 16384, 512, 512);
}